// Round 10
// baseline (282.947 us; speedup 1.0000x reference)
//
#include <hip/hip_runtime.h>
#include <hip/hip_bf16.h>

// CrossModalMDTA on gfx950 — round 10.
// q/k HBM round-trip eliminated: dwgram fuses depthwise-3x3 (q,k channels)
// with the gram MFMA — dw results live only in a double-buffered LDS tile.
// v keeps its round-trip (dw3x3_v) for the final GEMM. proj/final = round-8
// config (BN=128, split-K=64 dbuf).

typedef __attribute__((ext_vector_type(8))) short short8;   // 8 x bf16
typedef __attribute__((ext_vector_type(4))) float f32x4;    // MFMA accum

static __device__ __forceinline__ float b2f(unsigned short u) {
    return __uint_as_float(((unsigned)u) << 16);
}
static __device__ __forceinline__ unsigned short f2b(float f) {
    unsigned u = __float_as_uint(f);
    u += 0x7FFFu + ((u >> 16) & 1u);          // RNE
    return (unsigned short)(u >> 16);
}
static __device__ __forceinline__ unsigned short f2bh(float f) {
    union { __hip_bfloat16 h; unsigned short u; } cv;
    cv.h = __float2bfloat16(f);
    return cv.u;
}

__global__ void cvt_f2b_kernel(const float* __restrict__ src,
                               unsigned short* __restrict__ dst, int n) {
    int i = blockIdx.x * blockDim.x + threadIdx.x;
    if (i < n) dst[i] = f2b(src[i]);
}

// ---------------------------------------------------------------------------
// GEMM body (round-8): C[m,n] = sum_k A[m,k]*B[k,n], K=192, tile 192m x 128n,
// 4 waves, split-K=64 double-buffered.
// ---------------------------------------------------------------------------
template<typename Bty, typename Oty>
static __device__ __forceinline__ void gemm_body(
    const unsigned short* __restrict__ A,   // bf16 [192 x 192]
    const Bty* __restrict__ B,              // [192 x N] fp32 or bf16
    Oty* __restrict__ C)                    // [192 x N] bf16(ushort) or fp32
{
    constexpr long N = 16384;
    constexpr int K = 192;
    const int tid  = threadIdx.x;
    const int wave = tid >> 6;
    const int lane = tid & 63;
    const int l15  = lane & 15;
    const int g    = lane >> 4;
    const long n0  = (long)blockIdx.x * 128;

    __shared__ unsigned short Bs[2][128][72];   // 36.9 KB

    const int nc = tid & 127;
    const int kb = tid >> 7;

    float fv[4][8];
    unsigned short sv[4][8];

    auto load_regs = [&](int s) {
#pragma unroll
        for (int i = 0; i < 4; ++i) {
            const int kc = kb + 2 * i;
            const Bty* bp = B + (long)(s * 64 + kc * 8) * N + n0 + nc;
#pragma unroll
            for (int j = 0; j < 8; ++j) {
                if constexpr (sizeof(Bty) == 4) fv[i][j] = (float)bp[j * N];
                else                            sv[i][j] = bp[j * N];
            }
        }
    };
    auto write_lds = [&](int buf) {
#pragma unroll
        for (int i = 0; i < 4; ++i) {
            const int kc = kb + 2 * i;
            unsigned w[4];
#pragma unroll
            for (int t = 0; t < 4; ++t) {
                if constexpr (sizeof(Bty) == 4)
                    w[t] = (unsigned)f2bh(fv[i][2*t]) | ((unsigned)f2bh(fv[i][2*t+1]) << 16);
                else
                    w[t] = (unsigned)sv[i][2*t] | ((unsigned)sv[i][2*t+1] << 16);
            }
            uint4 pk = {w[0], w[1], w[2], w[3]};
            *reinterpret_cast<uint4*>(&Bs[buf][nc][kc * 8]) = pk;
        }
    };

    f32x4 acc[3][8];
#pragma unroll
    for (int i = 0; i < 3; ++i)
#pragma unroll
        for (int j = 0; j < 8; ++j) acc[i][j] = {0.f, 0.f, 0.f, 0.f};

    load_regs(0);
    write_lds(0);
    __syncthreads();

#pragma unroll
    for (int s = 0; s < 3; ++s) {
        const int buf = s & 1;
        if (s < 2) load_regs(s + 1);
#pragma unroll
        for (int s32 = 0; s32 < 2; ++s32) {
            short8 af[3];
#pragma unroll
            for (int mt = 0; mt < 3; ++mt)
                af[mt] = *reinterpret_cast<const short8*>(
                    A + (long)(wave * 48 + mt * 16 + l15) * K + s * 64 + s32 * 32 + g * 8);
            short8 bf[8];
#pragma unroll
            for (int nt = 0; nt < 8; ++nt)
                bf[nt] = *reinterpret_cast<const short8*>(
                    &Bs[buf][nt * 16 + l15][s32 * 32 + g * 8]);
#pragma unroll
            for (int nt = 0; nt < 8; ++nt)
#pragma unroll
                for (int mt = 0; mt < 3; ++mt)
                    acc[mt][nt] = __builtin_amdgcn_mfma_f32_16x16x32_bf16(
                        af[mt], bf[nt], acc[mt][nt], 0, 0, 0);
        }
        if (s < 2) {
            write_lds(buf ^ 1);
            __syncthreads();
        }
    }

#pragma unroll
    for (int mt = 0; mt < 3; ++mt) {
#pragma unroll
        for (int nt = 0; nt < 8; ++nt) {
            const int row = wave * 48 + mt * 16 + g * 4;
            const long col = n0 + nt * 16 + l15;
#pragma unroll
            for (int r = 0; r < 4; ++r) {
                const float v = acc[mt][nt][r];
                if constexpr (sizeof(Oty) == 4)
                    C[(long)(row + r) * N + col] = v;
                else
                    C[(long)(row + r) * N + col] = f2b(v);
            }
        }
    }
}

// fused q + kv projection: y==0 -> q0 ; y==1,2 -> kv0 halves
__global__ void __launch_bounds__(256) proj_gemm(
    const unsigned short* __restrict__ wq_b,
    const unsigned short* __restrict__ wkv_b,
    const float* __restrict__ f_opt,
    const float* __restrict__ f_sar,
    unsigned short* __restrict__ q0,
    unsigned short* __restrict__ kv0)
{
    constexpr long N = 16384;
    const int b = blockIdx.z;
    const int y = blockIdx.y;
    if (y == 0) {
        gemm_body<float, unsigned short>(
            wq_b, f_opt + (long)b * 192 * N, q0 + (long)b * 192 * N);
    } else {
        gemm_body<float, unsigned short>(
            wkv_b + (long)(y - 1) * 192 * 192,
            f_sar + (long)b * 192 * N,
            kv0 + ((long)b * 384 + (long)(y - 1) * 192) * N);
    }
}

// final: out = M_b @ v   (v = vbuf [B,192,N])
__global__ void __launch_bounds__(256) final_gemm(
    const unsigned short* __restrict__ Mmat,   // [B,192,192] bf16
    const unsigned short* __restrict__ v,
    float* __restrict__ out)
{
    constexpr long N = 16384;
    const int b = blockIdx.z;
    gemm_body<unsigned short, float>(
        Mmat + (long)b * 192 * 192, v + (long)b * 192 * N, out + (long)b * 192 * N);
}

// ---------------------------------------------------------------------------
// dwgram: fused depthwise-3x3 (q,k) + gram partial. Grid (16 chunks, 4 h, 8 b),
// 256 threads. Block = head h, image rows [8*chunk, 8*chunk+8). Per substep
// (one 128-px image row): dw for 96 channels -> LDS tile [96][136] bf16
// (double-buffered), then each wave MFMAs its 32-px k-step into acc[3][3].
// Epilogue: 4-wave LDS reduce -> Gpart; norm partials from pre-rounding fp32.
// ---------------------------------------------------------------------------
__global__ void __launch_bounds__(256, 2) dwgram(
    const unsigned short* __restrict__ q0,   // [B][192][N] bf16
    const unsigned short* __restrict__ kv0,  // [B][384][N] bf16 (k = 0..191)
    const float* __restrict__ w_qdw,         // [192][9]
    const float* __restrict__ w_kvdw,        // [384][9]
    float* __restrict__ Gpart,               // [B][4][16][2304]
    float* __restrict__ nqPart,              // [B][192][16]
    float* __restrict__ nkPart)              // [B][192][16]
{
    constexpr long NP = 16384;
    const int chunk = blockIdx.x;            // 0..15 (8 rows each)
    const int h     = blockIdx.y;
    const int b     = blockIdx.z;

    const int tid  = threadIdx.x;
    const int wave = tid >> 6;               // 0..3 = k-step
    const int lane = tid & 63;
    const int l15  = lane & 15;
    const int g    = lane >> 4;

    const int w0     = (tid & 15) * 8;       // px within row
    const int chBase = tid >> 4;             // 0..15

    __shared__ __align__(16) unsigned short smem[2][96][136];  // 51 KB dbuf

    // per-thread 6 tasks: channel ch_loc = tt*16 + chBase (0..95; <48 = q)
    const unsigned short* srcs[6];
    float wt[6][9];
    float nacc[6];
#pragma unroll
    for (int tt = 0; tt < 6; ++tt) {
        const int ch_loc = tt * 16 + chBase;
        const float* wp;
        if (ch_loc < 48) {
            const int c = 48 * h + ch_loc;
            srcs[tt] = q0 + ((long)b * 192 + c) * NP;
            wp = w_qdw + c * 9;
        } else {
            const int c = 48 * h + ch_loc - 48;
            srcs[tt] = kv0 + ((long)b * 384 + c) * NP;
            wp = w_kvdw + c * 9;
        }
#pragma unroll
        for (int i = 0; i < 9; ++i) wt[tt][i] = wp[i];
        nacc[tt] = 0.f;
    }

    f32x4 acc[3][3];
#pragma unroll
    for (int i = 0; i < 3; ++i)
#pragma unroll
        for (int j = 0; j < 3; ++j) acc[i][j] = {0.f, 0.f, 0.f, 0.f};

    auto dw_step = [&](int s, int buf) {
        const int r = chunk * 8 + s;         // image row, always 0..127
#pragma unroll
        for (int tt = 0; tt < 6; ++tt) {
            float a8[8] = {0, 0, 0, 0, 0, 0, 0, 0};
#pragma unroll
            for (int dy = 0; dy < 3; ++dy) {
                const int hy = r + dy - 1;   // uniform across block
                if (hy < 0 || hy > 127) continue;
                const unsigned short* row = srcs[tt] + hy * 128 + w0;
                float rr[10];
                const short8 v = *reinterpret_cast<const short8*>(row);
#pragma unroll
                for (int i = 0; i < 8; ++i) rr[i + 1] = b2f((unsigned short)v[i]);
                const float left  = __shfl_up(rr[8], 1);
                const float right = __shfl_down(rr[1], 1);
                rr[0] = (l15 > 0)  ? left  : 0.f;
                rr[9] = (l15 < 15) ? right : 0.f;
#pragma unroll
                for (int j = 0; j < 8; ++j)
                    a8[j] += wt[tt][dy*3+0]*rr[j] + wt[tt][dy*3+1]*rr[j+1]
                           + wt[tt][dy*3+2]*rr[j+2];
            }
            float ss = 0.f;
#pragma unroll
            for (int j = 0; j < 8; ++j) ss += a8[j] * a8[j];
            nacc[tt] += ss;
            unsigned u[4];
#pragma unroll
            for (int t2 = 0; t2 < 4; ++t2)
                u[t2] = (unsigned)f2bh(a8[2*t2]) | ((unsigned)f2bh(a8[2*t2+1]) << 16);
            uint4 pk = {u[0], u[1], u[2], u[3]};
            *reinterpret_cast<uint4*>(&smem[buf][tt * 16 + chBase][w0]) = pk;
        }
    };

    auto mma_step = [&](int buf) {
        short8 af[3], bf[3];
#pragma unroll
        for (int mt = 0; mt < 3; ++mt)
            af[mt] = *reinterpret_cast<const short8*>(
                &smem[buf][mt * 16 + l15][wave * 32 + g * 8]);
#pragma unroll
        for (int nt = 0; nt < 3; ++nt)
            bf[nt] = *reinterpret_cast<const short8*>(
                &smem[buf][48 + nt * 16 + l15][wave * 32 + g * 8]);
#pragma unroll
        for (int mt = 0; mt < 3; ++mt)
#pragma unroll
            for (int nt = 0; nt < 3; ++nt)
                acc[mt][nt] = __builtin_amdgcn_mfma_f32_16x16x32_bf16(
                    af[mt], bf[nt], acc[mt][nt], 0, 0, 0);
    };

    dw_step(0, 0);
    __syncthreads();
#pragma unroll 1
    for (int s = 0; s < 8; ++s) {
        const int buf = s & 1;
        if (s < 7) dw_step(s + 1, buf ^ 1);  // overlaps mma below
        mma_step(buf);
        __syncthreads();
    }

    // epilogue: reduce 4 per-wave partials via aliased LDS
    float* Gt = reinterpret_cast<float*>(&smem[0][0][0]);   // 4*2304 floats fits
#pragma unroll
    for (int mt = 0; mt < 3; ++mt)
#pragma unroll
        for (int nt = 0; nt < 3; ++nt)
#pragma unroll
            for (int r = 0; r < 4; ++r)
                Gt[wave * 2304 + (mt*16 + g*4 + r) * 48 + nt*16 + l15] = acc[mt][nt][r];
    __syncthreads();

    float* gout = Gpart + (((long)(b * 4 + h)) * 16 + chunk) * 2304;
    for (int i = tid; i < 2304; i += 256)
        gout[i] = Gt[i] + Gt[2304 + i] + Gt[4608 + i] + Gt[6912 + i];

    // norm partials (16-lane groups share a channel)
#pragma unroll
    for (int tt = 0; tt < 6; ++tt) {
        float ssv = nacc[tt];
        ssv += __shfl_xor(ssv, 1);
        ssv += __shfl_xor(ssv, 2);
        ssv += __shfl_xor(ssv, 4);
        ssv += __shfl_xor(ssv, 8);
        if ((tid & 15) == 0) {
            const int ch_loc = tt * 16 + chBase;
            if (ch_loc < 48)
                nqPart[((long)b * 192 + 48 * h + ch_loc) * 16 + chunk] = ssv;
            else
                nkPart[((long)b * 192 + 48 * h + ch_loc - 48) * 16 + chunk] = ssv;
        }
    }
}

// ---------------------------------------------------------------------------
// depthwise 3x3 for v only (round-8 body, halo via shuffles, no norms).
// ---------------------------------------------------------------------------
__global__ void __launch_bounds__(256) dw3x3_v(
    const unsigned short* __restrict__ kv0,  // [B][384][N] (v = ch 192..383)
    unsigned short* __restrict__ vbuf,       // [B][192][N]
    const float* __restrict__ w_kvdw)        // [384][9]
{
    const int b  = blockIdx.z;
    const int t  = blockIdx.x * 256 + threadIdx.x;
    const int l16 = threadIdx.x & 15;
    const int w0 = l16 * 8;
    const int hh = (t >> 4) & 127;
    const int c  = t >> 11;                  // 0..191

    const unsigned short* s = kv0 + ((long)b * 384 + 192 + c) * 16384;
    unsigned short* d = vbuf + ((long)b * 192 + c) * 16384;
    const float* wp = w_kvdw + (192 + c) * 9;

    float wt[9];
#pragma unroll
    for (int i = 0; i < 9; ++i) wt[i] = wp[i];

    float acc[8] = {0, 0, 0, 0, 0, 0, 0, 0};
#pragma unroll
    for (int dy = 0; dy < 3; ++dy) {
        const int hy = hh + dy - 1;
        if (hy < 0 || hy > 127) continue;
        const unsigned short* row = s + hy * 128 + w0;
        float r[10];
        const short8 v = *reinterpret_cast<const short8*>(row);
#pragma unroll
        for (int i = 0; i < 8; ++i) r[i + 1] = b2f((unsigned short)v[i]);
        const float left  = __shfl_up(r[8], 1);
        const float right = __shfl_down(r[1], 1);
        r[0] = (l16 > 0)  ? left  : 0.f;
        r[9] = (l16 < 15) ? right : 0.f;
#pragma unroll
        for (int j = 0; j < 8; ++j)
            acc[j] += wt[dy*3+0]*r[j] + wt[dy*3+1]*r[j+1] + wt[dy*3+2]*r[j+2];
    }

    short8 o;
#pragma unroll
    for (int j = 0; j < 8; ++j) o[j] = (short)f2b(acc[j]);
    *reinterpret_cast<short8*>(d + hh * 128 + w0) = o;
}

// ---------------------------------------------------------------------------
// Per (b,h): reduce partials, softmax(G/(nq*nk)*T), fold w_out:
// M[c, 48h+e] = sum_d w_out[c, 48h+d] * attn[d,e]
// ---------------------------------------------------------------------------
__global__ void __launch_bounds__(256) attn_m_kernel(
    const float* __restrict__ Gpart,        // [B,4,16,2304]
    const float* __restrict__ nqPart,       // [B,192,16]
    const float* __restrict__ nkPart,       // [B,192,16]
    const float* __restrict__ w_out,        // [192,192] fp32
    const float* __restrict__ temperature,  // [4]
    unsigned short* __restrict__ Mmat)      // [B,192,192] bf16
{
    const int blk = blockIdx.x;
    const int b = blk >> 2, h = blk & 3;
    const int tid = threadIdx.x;
    __shared__ float G[2304];
    __shared__ float At[2304];
    __shared__ float nqv[48], nkv[48];

    const long base = ((long)(b * 4 + h)) * 16;
    for (int i = tid; i < 2304; i += 256) {
        float s = 0.f;
        for (int c = 0; c < 16; ++c) s += Gpart[(base + c) * 2304 + i];
        G[i] = s;
    }
    if (tid < 96) {
        const int isK = tid >= 48;
        const int d = tid - 48 * isK;
        const float* p = (isK ? nkPart : nqPart) + ((long)b * 192 + h * 48 + d) * 16;
        float s = 0.f;
        for (int i = 0; i < 16; ++i) s += p[i];
        const float nrm = fmaxf(sqrtf(s), 1e-12f);
        if (isK) nkv[d] = nrm; else nqv[d] = nrm;
    }
    __syncthreads();

    const float T = temperature[h];
    if (tid < 48) {
        const int d = tid;
        const float scale = T / nqv[d];
        float m = -1e30f;
        for (int e = 0; e < 48; ++e) {
            const float sv = G[d * 48 + e] * scale / nkv[e];
            At[d * 48 + e] = sv;
            m = fmaxf(m, sv);
        }
        float sum = 0.f;
        for (int e = 0; e < 48; ++e) {
            const float ex = expf(At[d * 48 + e] - m);
            At[d * 48 + e] = ex;
            sum += ex;
        }
        const float inv = 1.f / sum;
        for (int e = 0; e < 48; ++e) At[d * 48 + e] *= inv;
    }
    __syncthreads();

    for (int i = tid; i < 192 * 48; i += 256) {
        const int c = i / 48, e = i - (i / 48) * 48;
        const float* wrow = w_out + (long)c * 192 + h * 48;
        float s = 0.f;
        for (int d = 0; d < 48; ++d) s += wrow[d] * At[d * 48 + e];
        Mmat[((long)b * 192 + c) * 192 + h * 48 + e] = f2b(s);
    }
}

// ---------------------------------------------------------------------------
extern "C" void kernel_launch(void* const* d_in, const int* in_sizes, int n_in,
                              void* d_out, int out_size, void* d_ws, size_t ws_size,
                              hipStream_t stream)
{
    const float* f_opt  = (const float*)d_in[0];
    const float* f_sar  = (const float*)d_in[1];
    const float* w_q    = (const float*)d_in[2];
    const float* w_qdw  = (const float*)d_in[3];
    const float* w_kv   = (const float*)d_in[4];
    const float* w_kvdw = (const float*)d_in[5];
    const float* w_out  = (const float*)d_in[6];
    const float* temper = (const float*)d_in[7];
    float* out = (float*)d_out;

    const long N = 16384;
    char* ws = (char*)d_ws;
    size_t off = 0;
    auto alloc = [&](size_t bytes) -> void* {
        void* p = ws + off;
        off = (off + bytes + 255) & ~(size_t)255;
        return p;
    };

    unsigned short* wq_b  = (unsigned short*)alloc((size_t)192 * 192 * 2);
    unsigned short* wkv_b = (unsigned short*)alloc((size_t)384 * 192 * 2);
    unsigned short* Mmat  = (unsigned short*)alloc((size_t)8 * 192 * 192 * 2);
    float* Gpart  = (float*)alloc((size_t)8 * 4 * 16 * 2304 * 4);
    float* nqPart = (float*)alloc((size_t)8 * 192 * 16 * 4);
    float* nkPart = (float*)alloc((size_t)8 * 192 * 16 * 4);
    unsigned short* vbuf = (unsigned short*)alloc((size_t)8 * 192 * N * 2);
    unsigned short* q0   = (unsigned short*)alloc((size_t)8 * 192 * N * 2);
    unsigned short* kv0  = (unsigned short*)alloc((size_t)8 * 384 * N * 2);

    cvt_f2b_kernel<<<dim3((192*192 + 255) / 256), 256, 0, stream>>>(w_q,  wq_b,  192*192);
    cvt_f2b_kernel<<<dim3((384*192 + 255) / 256), 256, 0, stream>>>(w_kv, wkv_b, 384*192);

    proj_gemm<<<dim3(128, 3, 8), 256, 0, stream>>>(
        wq_b, wkv_b, f_opt, f_sar, q0, kv0);

    dwgram<<<dim3(16, 4, 8), 256, 0, stream>>>(
        q0, kv0, w_qdw, w_kvdw, Gpart, nqPart, nkPart);

    dw3x3_v<<<dim3(1536, 1, 8), 256, 0, stream>>>(kv0, vbuf, w_kvdw);

    attn_m_kernel<<<dim3(32), 256, 0, stream>>>(
        Gpart, nqPart, nkPart, w_out, temper, Mmat);

    final_gemm<<<dim3(128, 1, 8), 256, 0, stream>>>(Mmat, vbuf, out);
}

// Round 11
// 279.800 us; speedup vs baseline: 1.0112x; 1.0112x over previous
//
#include <hip/hip_runtime.h>
#include <hip/hip_bf16.h>

// CrossModalMDTA on gfx950 — round 11.
// vbuf round-trip eliminated: final_gemm fuses dw3x3(v) — block = image row r,
// dw computes B-tile [128px][200ch] in LDS from v0 rows r-1..r+1 (short8 +
// shfl halo), then 6-stage MFMA sweep. proj B loads widened to float2.

typedef __attribute__((ext_vector_type(8))) short short8;   // 8 x bf16
typedef __attribute__((ext_vector_type(4))) float f32x4;    // MFMA accum

static __device__ __forceinline__ float b2f(unsigned short u) {
    return __uint_as_float(((unsigned)u) << 16);
}
static __device__ __forceinline__ unsigned short f2b(float f) {
    unsigned u = __float_as_uint(f);
    u += 0x7FFFu + ((u >> 16) & 1u);          // RNE
    return (unsigned short)(u >> 16);
}
static __device__ __forceinline__ unsigned short f2bh(float f) {
    union { __hip_bfloat16 h; unsigned short u; } cv;
    cv.h = __float2bfloat16(f);
    return cv.u;
}

__global__ void cvt_f2b_kernel(const float* __restrict__ src,
                               unsigned short* __restrict__ dst, int n) {
    int i = blockIdx.x * blockDim.x + threadIdx.x;
    if (i < n) dst[i] = f2b(src[i]);
}

// ---------------------------------------------------------------------------
// proj GEMM body: C[m,n] = sum_k A[m,k]*B[k,n], K=192, fp32 B, tile 192x128,
// 4 waves, split-K=64 double-buffered, float2 B loads (512B/instr).
// ---------------------------------------------------------------------------
static __device__ __forceinline__ void gemm_body_f32(
    const unsigned short* __restrict__ A,   // bf16 [192 x 192]
    const float* __restrict__ B,            // [192 x N] fp32
    unsigned short* __restrict__ C)         // [192 x N] bf16
{
    constexpr long N = 16384;
    constexpr int K = 192;
    const int tid  = threadIdx.x;
    const int wave = tid >> 6;
    const int lane = tid & 63;
    const int l15  = lane & 15;
    const int g    = lane >> 4;
    const long n0  = (long)blockIdx.x * 128;

    __shared__ unsigned short Bs[2][128][72];   // 36.9 KB

    const int nc2 = (tid & 63) * 2;   // px pair
    const int kb  = tid >> 6;         // 0..3

    float2 fv[2][8];

    auto load_regs = [&](int s) {
#pragma unroll
        for (int i = 0; i < 2; ++i) {
            const int kc = kb * 2 + i;          // k-chunk 0..7
            const float* bp = B + (long)(s * 64 + kc * 8) * N + n0 + nc2;
#pragma unroll
            for (int j = 0; j < 8; ++j)
                fv[i][j] = *reinterpret_cast<const float2*>(bp + (long)j * N);
        }
    };
    auto write_lds = [&](int buf) {
#pragma unroll
        for (int i = 0; i < 2; ++i) {
            const int kc = kb * 2 + i;
#pragma unroll
            for (int p = 0; p < 2; ++p) {
                unsigned w[4];
#pragma unroll
                for (int t = 0; t < 4; ++t) {
                    const float lo = p ? fv[i][2*t].y   : fv[i][2*t].x;
                    const float hi = p ? fv[i][2*t+1].y : fv[i][2*t+1].x;
                    w[t] = (unsigned)f2bh(lo) | ((unsigned)f2bh(hi) << 16);
                }
                uint4 pk = {w[0], w[1], w[2], w[3]};
                *reinterpret_cast<uint4*>(&Bs[buf][nc2 + p][kc * 8]) = pk;
            }
        }
    };

    f32x4 acc[3][8];
#pragma unroll
    for (int i = 0; i < 3; ++i)
#pragma unroll
        for (int j = 0; j < 8; ++j) acc[i][j] = {0.f, 0.f, 0.f, 0.f};

    load_regs(0);
    write_lds(0);
    __syncthreads();

#pragma unroll
    for (int s = 0; s < 3; ++s) {
        const int buf = s & 1;
        if (s < 2) load_regs(s + 1);
#pragma unroll
        for (int s32 = 0; s32 < 2; ++s32) {
            short8 af[3];
#pragma unroll
            for (int mt = 0; mt < 3; ++mt)
                af[mt] = *reinterpret_cast<const short8*>(
                    A + (long)(wave * 48 + mt * 16 + l15) * K + s * 64 + s32 * 32 + g * 8);
            short8 bf[8];
#pragma unroll
            for (int nt = 0; nt < 8; ++nt)
                bf[nt] = *reinterpret_cast<const short8*>(
                    &Bs[buf][nt * 16 + l15][s32 * 32 + g * 8]);
#pragma unroll
            for (int nt = 0; nt < 8; ++nt)
#pragma unroll
                for (int mt = 0; mt < 3; ++mt)
                    acc[mt][nt] = __builtin_amdgcn_mfma_f32_16x16x32_bf16(
                        af[mt], bf[nt], acc[mt][nt], 0, 0, 0);
        }
        if (s < 2) {
            write_lds(buf ^ 1);
            __syncthreads();
        }
    }

#pragma unroll
    for (int mt = 0; mt < 3; ++mt) {
#pragma unroll
        for (int nt = 0; nt < 8; ++nt) {
            const int row = wave * 48 + mt * 16 + g * 4;
            const long col = n0 + nt * 16 + l15;
#pragma unroll
            for (int r = 0; r < 4; ++r)
                C[(long)(row + r) * N + col] = f2b(acc[mt][nt][r]);
        }
    }
}

// fused q + kv projection: y==0 -> q0 ; y==1,2 -> kv0 halves
__global__ void __launch_bounds__(256) proj_gemm(
    const unsigned short* __restrict__ wq_b,
    const unsigned short* __restrict__ wkv_b,
    const float* __restrict__ f_opt,
    const float* __restrict__ f_sar,
    unsigned short* __restrict__ q0,
    unsigned short* __restrict__ kv0)
{
    constexpr long N = 16384;
    const int b = blockIdx.z;
    const int y = blockIdx.y;
    if (y == 0) {
        gemm_body_f32(wq_b, f_opt + (long)b * 192 * N, q0 + (long)b * 192 * N);
    } else {
        gemm_body_f32(wkv_b + (long)(y - 1) * 192 * 192,
                      f_sar + (long)b * 192 * N,
                      kv0 + ((long)b * 384 + (long)(y - 1) * 192) * N);
    }
}

// ---------------------------------------------------------------------------
// final GEMM fused with dw3x3(v): block = (image row r, batch b).
// Phase 1: dw for 192 v-channels at row r from v0 rows r-1..r+1 into LDS
//          Bsv[px][ch] (ch-pair packed b32 writes).
// Phase 2: out[c][r*128+px] = sum_ch M[c][ch] * Bsv[px][ch] via MFMA,
//          6 k-stages, fragments read as ds_read_b128 (k=ch contiguous).
// ---------------------------------------------------------------------------
__global__ void __launch_bounds__(256) final_gemm_fused(
    const unsigned short* __restrict__ Mmat,   // [B,192,192] bf16
    const unsigned short* __restrict__ kv0,    // [B,384,N] (v = ch 192..383)
    const float* __restrict__ w_kvdw,          // [384][9]
    float* __restrict__ out)                   // [B,192,N] fp32
{
    constexpr long N = 16384;
    constexpr int K = 192;
    const int r = blockIdx.x;                  // image row 0..127
    const int b = blockIdx.z;
    const unsigned short* v0 = kv0 + ((long)b * 384 + 192) * N;
    const unsigned short* A  = Mmat + (long)b * 192 * 192;
    float* C = out + (long)b * 192 * N;

    const int tid  = threadIdx.x;
    const int wave = tid >> 6;
    const int lane = tid & 63;
    const int l15  = lane & 15;
    const int g    = lane >> 4;

    __shared__ __align__(16) unsigned short Bsv[128][200];   // [px][ch] 51.2 KB

    // ---- phase 1: dw. thread owns 6 ch-pairs x 8 px.
    const int l16   = tid & 15;
    const int pBase = l16 * 8;
    const int cp    = tid >> 4;                // 0..15

#pragma unroll
    for (int t6 = 0; t6 < 6; ++t6) {
        const int c0 = t6 * 32 + cp * 2;       // even channel of the pair
        float a8[2][8];
#pragma unroll
        for (int e = 0; e < 2; ++e)
#pragma unroll
            for (int j = 0; j < 8; ++j) a8[e][j] = 0.f;

#pragma unroll
        for (int e = 0; e < 2; ++e) {
            const int c = c0 + e;
            const float* wp = w_kvdw + (192 + c) * 9;
            float wt[9];
#pragma unroll
            for (int i = 0; i < 9; ++i) wt[i] = wp[i];
            const unsigned short* src = v0 + (long)c * N;
#pragma unroll
            for (int dy = 0; dy < 3; ++dy) {
                const int hy = r + dy - 1;
                if (hy < 0 || hy > 127) continue;
                const unsigned short* row = src + hy * 128 + pBase;
                float rr[10];
                const short8 v = *reinterpret_cast<const short8*>(row);
#pragma unroll
                for (int i = 0; i < 8; ++i) rr[i + 1] = b2f((unsigned short)v[i]);
                const float left  = __shfl_up(rr[8], 1);
                const float right = __shfl_down(rr[1], 1);
                rr[0] = (l16 > 0)  ? left  : 0.f;
                rr[9] = (l16 < 15) ? right : 0.f;
#pragma unroll
                for (int j = 0; j < 8; ++j)
                    a8[e][j] += wt[dy*3+0]*rr[j] + wt[dy*3+1]*rr[j+1]
                              + wt[dy*3+2]*rr[j+2];
            }
        }
        // pack pair -> LDS [px][ch]
#pragma unroll
        for (int j = 0; j < 8; ++j) {
            const unsigned u = (unsigned)f2bh(a8[0][j])
                             | ((unsigned)f2bh(a8[1][j]) << 16);
            *reinterpret_cast<unsigned*>(&Bsv[pBase + j][c0]) = u;
        }
    }
    __syncthreads();

    // ---- phase 2: GEMM. A = Mmat (L2-hot), B = Bsv.
    f32x4 acc[3][8];
#pragma unroll
    for (int i = 0; i < 3; ++i)
#pragma unroll
        for (int j = 0; j < 8; ++j) acc[i][j] = {0.f, 0.f, 0.f, 0.f};

#pragma unroll
    for (int s = 0; s < 6; ++s) {
        short8 af[3];
#pragma unroll
        for (int mt = 0; mt < 3; ++mt)
            af[mt] = *reinterpret_cast<const short8*>(
                A + (long)(wave * 48 + mt * 16 + l15) * K + s * 32 + g * 8);
        short8 bf[8];
#pragma unroll
        for (int nt = 0; nt < 8; ++nt)
            bf[nt] = *reinterpret_cast<const short8*>(
                &Bsv[nt * 16 + l15][s * 32 + g * 8]);
#pragma unroll
        for (int nt = 0; nt < 8; ++nt)
#pragma unroll
            for (int mt = 0; mt < 3; ++mt)
                acc[mt][nt] = __builtin_amdgcn_mfma_f32_16x16x32_bf16(
                    af[mt], bf[nt], acc[mt][nt], 0, 0, 0);
    }

    const long n0 = (long)r * 128;
#pragma unroll
    for (int mt = 0; mt < 3; ++mt) {
#pragma unroll
        for (int nt = 0; nt < 8; ++nt) {
            const int row = wave * 48 + mt * 16 + g * 4;
            const long col = n0 + nt * 16 + l15;
#pragma unroll
            for (int rr2 = 0; rr2 < 4; ++rr2)
                C[(long)(row + rr2) * N + col] = acc[mt][nt][rr2];
        }
    }
}

// ---------------------------------------------------------------------------
// dwgram: fused depthwise-3x3 (q,k) + gram partial (round-10, unchanged).
// ---------------------------------------------------------------------------
__global__ void __launch_bounds__(256, 2) dwgram(
    const unsigned short* __restrict__ q0,   // [B][192][N] bf16
    const unsigned short* __restrict__ kv0,  // [B][384][N] bf16 (k = 0..191)
    const float* __restrict__ w_qdw,         // [192][9]
    const float* __restrict__ w_kvdw,        // [384][9]
    float* __restrict__ Gpart,               // [B][4][16][2304]
    float* __restrict__ nqPart,              // [B][192][16]
    float* __restrict__ nkPart)              // [B][192][16]
{
    constexpr long NP = 16384;
    const int chunk = blockIdx.x;            // 0..15 (8 rows each)
    const int h     = blockIdx.y;
    const int b     = blockIdx.z;

    const int tid  = threadIdx.x;
    const int wave = tid >> 6;               // 0..3 = k-step
    const int lane = tid & 63;
    const int l15  = lane & 15;
    const int g    = lane >> 4;

    const int w0     = (tid & 15) * 8;
    const int chBase = tid >> 4;             // 0..15

    __shared__ __align__(16) unsigned short smem[2][96][136];  // 51 KB dbuf

    const unsigned short* srcs[6];
    float wt[6][9];
    float nacc[6];
#pragma unroll
    for (int tt = 0; tt < 6; ++tt) {
        const int ch_loc = tt * 16 + chBase;
        const float* wp;
        if (ch_loc < 48) {
            const int c = 48 * h + ch_loc;
            srcs[tt] = q0 + ((long)b * 192 + c) * NP;
            wp = w_qdw + c * 9;
        } else {
            const int c = 48 * h + ch_loc - 48;
            srcs[tt] = kv0 + ((long)b * 384 + c) * NP;
            wp = w_kvdw + c * 9;
        }
#pragma unroll
        for (int i = 0; i < 9; ++i) wt[tt][i] = wp[i];
        nacc[tt] = 0.f;
    }

    f32x4 acc[3][3];
#pragma unroll
    for (int i = 0; i < 3; ++i)
#pragma unroll
        for (int j = 0; j < 3; ++j) acc[i][j] = {0.f, 0.f, 0.f, 0.f};

    auto dw_step = [&](int s, int buf) {
        const int r = chunk * 8 + s;
#pragma unroll
        for (int tt = 0; tt < 6; ++tt) {
            float a8[8] = {0, 0, 0, 0, 0, 0, 0, 0};
#pragma unroll
            for (int dy = 0; dy < 3; ++dy) {
                const int hy = r + dy - 1;
                if (hy < 0 || hy > 127) continue;
                const unsigned short* row = srcs[tt] + hy * 128 + w0;
                float rr[10];
                const short8 v = *reinterpret_cast<const short8*>(row);
#pragma unroll
                for (int i = 0; i < 8; ++i) rr[i + 1] = b2f((unsigned short)v[i]);
                const float left  = __shfl_up(rr[8], 1);
                const float right = __shfl_down(rr[1], 1);
                rr[0] = (l15 > 0)  ? left  : 0.f;
                rr[9] = (l15 < 15) ? right : 0.f;
#pragma unroll
                for (int j = 0; j < 8; ++j)
                    a8[j] += wt[tt][dy*3+0]*rr[j] + wt[tt][dy*3+1]*rr[j+1]
                           + wt[tt][dy*3+2]*rr[j+2];
            }
            float ss = 0.f;
#pragma unroll
            for (int j = 0; j < 8; ++j) ss += a8[j] * a8[j];
            nacc[tt] += ss;
            unsigned u[4];
#pragma unroll
            for (int t2 = 0; t2 < 4; ++t2)
                u[t2] = (unsigned)f2bh(a8[2*t2]) | ((unsigned)f2bh(a8[2*t2+1]) << 16);
            uint4 pk = {u[0], u[1], u[2], u[3]};
            *reinterpret_cast<uint4*>(&smem[buf][tt * 16 + chBase][w0]) = pk;
        }
    };

    auto mma_step = [&](int buf) {
        short8 af[3], bf[3];
#pragma unroll
        for (int mt = 0; mt < 3; ++mt)
            af[mt] = *reinterpret_cast<const short8*>(
                &smem[buf][mt * 16 + l15][wave * 32 + g * 8]);
#pragma unroll
        for (int nt = 0; nt < 3; ++nt)
            bf[nt] = *reinterpret_cast<const short8*>(
                &smem[buf][48 + nt * 16 + l15][wave * 32 + g * 8]);
#pragma unroll
        for (int mt = 0; mt < 3; ++mt)
#pragma unroll
            for (int nt = 0; nt < 3; ++nt)
                acc[mt][nt] = __builtin_amdgcn_mfma_f32_16x16x32_bf16(
                    af[mt], bf[nt], acc[mt][nt], 0, 0, 0);
    };

    dw_step(0, 0);
    __syncthreads();
#pragma unroll 1
    for (int s = 0; s < 8; ++s) {
        const int buf = s & 1;
        if (s < 7) dw_step(s + 1, buf ^ 1);
        mma_step(buf);
        __syncthreads();
    }

    float* Gt = reinterpret_cast<float*>(&smem[0][0][0]);
#pragma unroll
    for (int mt = 0; mt < 3; ++mt)
#pragma unroll
        for (int nt = 0; nt < 3; ++nt)
#pragma unroll
            for (int r = 0; r < 4; ++r)
                Gt[wave * 2304 + (mt*16 + g*4 + r) * 48 + nt*16 + l15] = acc[mt][nt][r];
    __syncthreads();

    float* gout = Gpart + (((long)(b * 4 + h)) * 16 + chunk) * 2304;
    for (int i = tid; i < 2304; i += 256)
        gout[i] = Gt[i] + Gt[2304 + i] + Gt[4608 + i] + Gt[6912 + i];

#pragma unroll
    for (int tt = 0; tt < 6; ++tt) {
        float ssv = nacc[tt];
        ssv += __shfl_xor(ssv, 1);
        ssv += __shfl_xor(ssv, 2);
        ssv += __shfl_xor(ssv, 4);
        ssv += __shfl_xor(ssv, 8);
        if ((tid & 15) == 0) {
            const int ch_loc = tt * 16 + chBase;
            if (ch_loc < 48)
                nqPart[((long)b * 192 + 48 * h + ch_loc) * 16 + chunk] = ssv;
            else
                nkPart[((long)b * 192 + 48 * h + ch_loc - 48) * 16 + chunk] = ssv;
        }
    }
}

// ---------------------------------------------------------------------------
// Per (b,h): reduce partials, softmax(G/(nq*nk)*T), fold w_out:
// M[c, 48h+e] = sum_d w_out[c, 48h+d] * attn[d,e]
// ---------------------------------------------------------------------------
__global__ void __launch_bounds__(256) attn_m_kernel(
    const float* __restrict__ Gpart,        // [B,4,16,2304]
    const float* __restrict__ nqPart,       // [B,192,16]
    const float* __restrict__ nkPart,       // [B,192,16]
    const float* __restrict__ w_out,        // [192,192] fp32
    const float* __restrict__ temperature,  // [4]
    unsigned short* __restrict__ Mmat)      // [B,192,192] bf16
{
    const int blk = blockIdx.x;
    const int b = blk >> 2, h = blk & 3;
    const int tid = threadIdx.x;
    __shared__ float G[2304];
    __shared__ float At[2304];
    __shared__ float nqv[48], nkv[48];

    const long base = ((long)(b * 4 + h)) * 16;
    for (int i = tid; i < 2304; i += 256) {
        float s = 0.f;
        for (int c = 0; c < 16; ++c) s += Gpart[(base + c) * 2304 + i];
        G[i] = s;
    }
    if (tid < 96) {
        const int isK = tid >= 48;
        const int d = tid - 48 * isK;
        const float* p = (isK ? nkPart : nqPart) + ((long)b * 192 + h * 48 + d) * 16;
        float s = 0.f;
        for (int i = 0; i < 16; ++i) s += p[i];
        const float nrm = fmaxf(sqrtf(s), 1e-12f);
        if (isK) nkv[d] = nrm; else nqv[d] = nrm;
    }
    __syncthreads();

    const float T = temperature[h];
    if (tid < 48) {
        const int d = tid;
        const float scale = T / nqv[d];
        float m = -1e30f;
        for (int e = 0; e < 48; ++e) {
            const float sv = G[d * 48 + e] * scale / nkv[e];
            At[d * 48 + e] = sv;
            m = fmaxf(m, sv);
        }
        float sum = 0.f;
        for (int e = 0; e < 48; ++e) {
            const float ex = expf(At[d * 48 + e] - m);
            At[d * 48 + e] = ex;
            sum += ex;
        }
        const float inv = 1.f / sum;
        for (int e = 0; e < 48; ++e) At[d * 48 + e] *= inv;
    }
    __syncthreads();

    for (int i = tid; i < 192 * 48; i += 256) {
        const int c = i / 48, e = i - (i / 48) * 48;
        const float* wrow = w_out + (long)c * 192 + h * 48;
        float s = 0.f;
        for (int d = 0; d < 48; ++d) s += wrow[d] * At[d * 48 + e];
        Mmat[((long)b * 192 + c) * 192 + h * 48 + e] = f2b(s);
    }
}

// ---------------------------------------------------------------------------
extern "C" void kernel_launch(void* const* d_in, const int* in_sizes, int n_in,
                              void* d_out, int out_size, void* d_ws, size_t ws_size,
                              hipStream_t stream)
{
    const float* f_opt  = (const float*)d_in[0];
    const float* f_sar  = (const float*)d_in[1];
    const float* w_q    = (const float*)d_in[2];
    const float* w_qdw  = (const float*)d_in[3];
    const float* w_kv   = (const float*)d_in[4];
    const float* w_kvdw = (const float*)d_in[5];
    const float* w_out  = (const float*)d_in[6];
    const float* temper = (const float*)d_in[7];
    float* out = (float*)d_out;

    const long N = 16384;
    char* ws = (char*)d_ws;
    size_t off = 0;
    auto alloc = [&](size_t bytes) -> void* {
        void* p = ws + off;
        off = (off + bytes + 255) & ~(size_t)255;
        return p;
    };

    unsigned short* wq_b  = (unsigned short*)alloc((size_t)192 * 192 * 2);
    unsigned short* wkv_b = (unsigned short*)alloc((size_t)384 * 192 * 2);
    unsigned short* Mmat  = (unsigned short*)alloc((size_t)8 * 192 * 192 * 2);
    float* Gpart  = (float*)alloc((size_t)8 * 4 * 16 * 2304 * 4);
    float* nqPart = (float*)alloc((size_t)8 * 192 * 16 * 4);
    float* nkPart = (float*)alloc((size_t)8 * 192 * 16 * 4);
    unsigned short* q0   = (unsigned short*)alloc((size_t)8 * 192 * N * 2);
    unsigned short* kv0  = (unsigned short*)alloc((size_t)8 * 384 * N * 2);

    cvt_f2b_kernel<<<dim3((192*192 + 255) / 256), 256, 0, stream>>>(w_q,  wq_b,  192*192);
    cvt_f2b_kernel<<<dim3((384*192 + 255) / 256), 256, 0, stream>>>(w_kv, wkv_b, 384*192);

    proj_gemm<<<dim3(128, 3, 8), 256, 0, stream>>>(
        wq_b, wkv_b, f_opt, f_sar, q0, kv0);

    dwgram<<<dim3(16, 4, 8), 256, 0, stream>>>(
        q0, kv0, w_qdw, w_kvdw, Gpart, nqPart, nkPart);

    attn_m_kernel<<<dim3(32), 256, 0, stream>>>(
        Gpart, nqPart, nkPart, w_out, temper, Mmat);

    final_gemm_fused<<<dim3(128, 1, 8), 256, 0, stream>>>(
        Mmat, kv0, w_kvdw, out);
}